// Round 6
// baseline (229.672 us; speedup 1.0000x reference)
//
#include <hip/hip_runtime.h>
#include <math.h>
#include <stdint.h>

#define N_NODES 16384
#define N_EDGES 262144
#define HID 128
#define NRBF 20
#define CUTOFF 5.0f
#define PI_F 3.14159265358979323846f

// coef record: 24 floats = 96 B: [0..2]=ux,uy,uz [3]=fcut [4..23]=c0..c19
#define CSTRIDE 24

__device__ inline unsigned short f2bf(float f) {
    unsigned int u = __float_as_uint(f);
    u = u + 0x7FFFu + ((u >> 16) & 1u);
    return (unsigned short)(u >> 16);
}
__device__ inline uint32_t pack2(float lo, float hi) {
    return (uint32_t)f2bf(lo) | ((uint32_t)f2bf(hi) << 16);
}
__device__ inline float blo(uint32_t u) { return __uint_as_float(u << 16); }
__device__ inline float bhi(uint32_t u) { return __uint_as_float(u & 0xFFFF0000u); }

// ---------------------------------------------------------------------------
// Kernel 1: phi = silu(s@W1+b1)@W2+b2, packed with v as bf16 pairs into
// g[node][384]: (phi0,phi1)(phi2,v0)(v1,v2)
// ---------------------------------------------------------------------------
#define NB 16
__global__ __launch_bounds__(128) void phi_kernel(
    const float* __restrict__ s, const float* __restrict__ v,
    const float* __restrict__ W1, const float* __restrict__ b1,
    const float* __restrict__ W2, const float* __restrict__ b2,
    uint32_t* __restrict__ g)
{
    __shared__ float sL[NB][HID];
    __shared__ float hL[NB][HID];
    const int t = threadIdx.x;
    const int node0 = blockIdx.x * NB;

    #pragma unroll
    for (int i = 0; i < NB; ++i)
        sL[i][t] = s[(size_t)(node0 + i) * HID + t];
    __syncthreads();

    float h[NB];
    const float bb1 = b1[t];
    #pragma unroll
    for (int i = 0; i < NB; ++i) h[i] = bb1;

    for (int k = 0; k < HID; k += 4) {
        float w[4];
        #pragma unroll
        for (int j = 0; j < 4; ++j) w[j] = W1[(size_t)(k + j) * HID + t];
        #pragma unroll
        for (int i = 0; i < NB; ++i) {
            const float4 sv = *reinterpret_cast<const float4*>(&sL[i][k]);
            h[i] += sv.x * w[0] + sv.y * w[1] + sv.z * w[2] + sv.w * w[3];
        }
    }
    #pragma unroll
    for (int i = 0; i < NB; ++i) {
        const float x = h[i];
        h[i] = x / (1.0f + expf(-x));
    }
    #pragma unroll
    for (int i = 0; i < NB; ++i) hL[i][t] = h[i];
    __syncthreads();

    float a0[NB], a1[NB], a2[NB];
    #pragma unroll
    for (int i = 0; i < NB; ++i) { a0[i] = 0.f; a1[i] = 0.f; a2[i] = 0.f; }

    for (int k = 0; k < HID; k += 4) {
        float w0[4], w1[4], w2[4];
        #pragma unroll
        for (int j = 0; j < 4; ++j) {
            const size_t row = (size_t)(k + j) * 384;
            w0[j] = W2[row + t];
            w1[j] = W2[row + 128 + t];
            w2[j] = W2[row + 256 + t];
        }
        #pragma unroll
        for (int i = 0; i < NB; ++i) {
            const float4 hv = *reinterpret_cast<const float4*>(&hL[i][k]);
            a0[i] += hv.x * w0[0] + hv.y * w0[1] + hv.z * w0[2] + hv.w * w0[3];
            a1[i] += hv.x * w1[0] + hv.y * w1[1] + hv.z * w1[2] + hv.w * w1[3];
            a2[i] += hv.x * w2[0] + hv.y * w2[1] + hv.z * w2[2] + hv.w * w2[3];
        }
    }
    const float bb2a = b2[t], bb2b = b2[128 + t], bb2c = b2[256 + t];
    #pragma unroll
    for (int i = 0; i < NB; ++i) {
        const size_t nrow = (size_t)(node0 + i) * 384;
        const float p0 = a0[i] + bb2a;
        const float p1 = a1[i] + bb2b;
        const float p2 = a2[i] + bb2c;
        const float v0 = v[nrow + t];
        const float v1 = v[nrow + 128 + t];
        const float v2 = v[nrow + 256 + t];
        g[nrow + t]       = pack2(p0, p1);
        g[nrow + 128 + t] = pack2(p2, v0);
        g[nrow + 256 + t] = pack2(v1, v2);
    }
}

// ---------------------------------------------------------------------------
// CSR build: histogram -> scan -> scatter (SoA: soff[]=src*384 + coef[])
// ---------------------------------------------------------------------------
__global__ __launch_bounds__(256) void hist_kernel(const int* __restrict__ edst,
                                                   int* __restrict__ cnt)
{
    const int e = blockIdx.x * 256 + threadIdx.x;
    if (e < N_EDGES) atomicAdd(&cnt[edst[e]], 1);
}

__global__ __launch_bounds__(256) void scan_kernel(const int* __restrict__ cnt,
                                                   int* __restrict__ row_ptr,
                                                   int* __restrict__ cur)
{
    __shared__ int part[256];
    const int tid = threadIdx.x;
    const int4* c4 = (const int4*)cnt;

    int4 loc[16];
    int s = 0;
    #pragma unroll
    for (int j = 0; j < 16; ++j) {
        loc[j] = c4[tid * 16 + j];
        s += loc[j].x + loc[j].y + loc[j].z + loc[j].w;
    }
    part[tid] = s;
    __syncthreads();
    #pragma unroll
    for (int d = 1; d < 256; d <<= 1) {
        const int add = (tid >= d) ? part[tid - d] : 0;
        __syncthreads();
        part[tid] += add;
        __syncthreads();
    }
    int off = (tid == 0) ? 0 : part[tid - 1];
    const int base = tid * 64;
    #pragma unroll
    for (int j = 0; j < 16; ++j) {
        const int4 q = loc[j];
        row_ptr[base + j*4 + 0] = off; cur[base + j*4 + 0] = off; off += q.x;
        row_ptr[base + j*4 + 1] = off; cur[base + j*4 + 1] = off; off += q.y;
        row_ptr[base + j*4 + 2] = off; cur[base + j*4 + 2] = off; off += q.z;
        row_ptr[base + j*4 + 3] = off; cur[base + j*4 + 3] = off; off += q.w;
    }
    if (tid == 255) row_ptr[16384] = off;
}

__global__ __launch_bounds__(256) void scatter_kernel(
    const float* __restrict__ r_ij, const int* __restrict__ esrc,
    const int* __restrict__ edst, int* __restrict__ cur,
    int* __restrict__ soff, float* __restrict__ coef)
{
    const int e = blockIdx.x * 256 + threadIdx.x;
    if (e >= N_EDGES) return;
    const float rx = r_ij[(size_t)e * 3 + 0];
    const float ry = r_ij[(size_t)e * 3 + 1];
    const float rz = r_ij[(size_t)e * 3 + 2];
    const float d = sqrtf(rx * rx + ry * ry + rz * rz);
    const float inv_d = 1.0f / d;
    float sx, cx;
    sincosf((PI_F / CUTOFF) * d, &sx, &cx);
    const float fcut = (d < CUTOFF) ? 0.5f * (cx + 1.0f) : 0.0f;

    float cf[NRBF];
    const float gfac = inv_d * fcut;
    const float twocx = 2.0f * cx;
    float sm1 = sx, sm2 = 0.0f;
    cf[0] = sx * gfac;
    #pragma unroll
    for (int n = 1; n < NRBF; ++n) {
        const float sn = twocx * sm1 - sm2;
        sm2 = sm1; sm1 = sn;
        cf[n] = sn * gfac;
    }

    const int pos = atomicAdd(&cur[edst[e]], 1);
    soff[pos] = esrc[e] * 384;          // pre-scaled row offset
    float4* c4 = (float4*)(coef + (size_t)pos * CSTRIDE);
    c4[0] = make_float4(rx * inv_d, ry * inv_d, rz * inv_d, fcut);
    c4[1] = make_float4(cf[0],  cf[1],  cf[2],  cf[3]);
    c4[2] = make_float4(cf[4],  cf[5],  cf[6],  cf[7]);
    c4[3] = make_float4(cf[8],  cf[9],  cf[10], cf[11]);
    c4[4] = make_float4(cf[12], cf[13], cf[14], cf[15]);
    c4[5] = make_float4(cf[16], cf[17], cf[18], cf[19]);
}

// ---------------------------------------------------------------------------
// Gather: node per 128-thread group; batch-4 edges; A/B ping-pong prefetch
// (24 gather words in flight, no register copies); scalar coef/soff loads;
// gather addresses = SGPR row base + shared ch voffset + imm offsets.
// ---------------------------------------------------------------------------
__global__ __launch_bounds__(256, 4) void gather_kernel(
    const uint32_t* __restrict__ gbuf, const int* __restrict__ soff,
    const float* __restrict__ coef, const int* __restrict__ row_ptr,
    const float* __restrict__ Wrbf, const float* __restrict__ brbf,
    float* __restrict__ dv, float* __restrict__ ds)
{
    const int ch   = threadIdx.x & 127;
    const int node = blockIdx.x * 2 + (threadIdx.x >> 7);

    float wr0[NRBF + 1], wr1[NRBF + 1], wr2[NRBF + 1];
    #pragma unroll
    for (int n = 0; n < NRBF; ++n) {
        wr0[n] = Wrbf[n * 384 + ch];
        wr1[n] = Wrbf[n * 384 + 128 + ch];
        wr2[n] = Wrbf[n * 384 + 256 + ch];
    }
    wr0[NRBF] = brbf[ch];
    wr1[NRBF] = brbf[128 + ch];
    wr2[NRBF] = brbf[256 + ch];

    const int beg = row_ptr[node];
    const int end = row_ptr[node + 1];
    const int nb  = (end - beg) >> 2;

    float a0 = 0.f, a1 = 0.f, a2 = 0.f, as = 0.f;

    uint32_t A[12], B[12];

#define LOADB(P, bi) do {                                                     \
    const int* sp_ = soff + __builtin_amdgcn_readfirstlane(beg + (bi) * 4);   \
    const uint32_t* g0_ = gbuf + sp_[0] + ch;                                 \
    const uint32_t* g1_ = gbuf + sp_[1] + ch;                                 \
    const uint32_t* g2_ = gbuf + sp_[2] + ch;                                 \
    const uint32_t* g3_ = gbuf + sp_[3] + ch;                                 \
    P[0] = g0_[0]; P[1]  = g0_[128]; P[2]  = g0_[256];                        \
    P[3] = g1_[0]; P[4]  = g1_[128]; P[5]  = g1_[256];                        \
    P[6] = g2_[0]; P[7]  = g2_[128]; P[8]  = g2_[256];                        \
    P[9] = g3_[0]; P[10] = g3_[128]; P[11] = g3_[256];                        \
} while (0)

#define CONSUME(P, bi) do {                                                   \
    const float* cp_ = coef +                                                 \
        (size_t)__builtin_amdgcn_readfirstlane(beg + (bi) * 4) * CSTRIDE;     \
    _Pragma("unroll")                                                         \
    for (int k = 0; k < 4; ++k) {                                             \
        const float ux = cp_[k * CSTRIDE + 0];                                \
        const float uy = cp_[k * CSTRIDE + 1];                                \
        const float uz = cp_[k * CSTRIDE + 2];                                \
        const float fc = cp_[k * CSTRIDE + 3];                                \
        float W0 = fc * wr0[NRBF];                                            \
        float W1 = fc * wr1[NRBF];                                            \
        float W2 = fc * wr2[NRBF];                                            \
        _Pragma("unroll")                                                     \
        for (int n = 0; n < NRBF; ++n) {                                      \
            const float c = cp_[k * CSTRIDE + 4 + n];                         \
            W0 += c * wr0[n];                                                 \
            W1 += c * wr1[n];                                                 \
            W2 += c * wr2[n];                                                 \
        }                                                                     \
        const uint32_t p0 = P[k*3], p1 = P[k*3+1], p2 = P[k*3+2];             \
        const float xv = blo(p0) * W0;                                        \
        const float xs = bhi(p0) * W1;                                        \
        const float xd = blo(p1) * W2;                                        \
        a0 += bhi(p1) * xv + ux * xd;                                         \
        a1 += blo(p2) * xv + uy * xd;                                         \
        a2 += bhi(p2) * xv + uz * xd;                                         \
        as += xs;                                                             \
    }                                                                         \
} while (0)

    if (nb >= 2) {
        LOADB(A, 0);
        LOADB(B, 1);
        int b = 0;
        for (; b + 2 < nb; b += 2) {
            CONSUME(A, b);
            LOADB(A, b + 2);
            CONSUME(B, b + 1);
            const int bn = (b + 3 < nb) ? (b + 3) : (nb - 1);
            LOADB(B, bn);
        }
        CONSUME(A, b);
        if (nb - b == 2) CONSUME(B, b + 1);
    } else if (nb == 1) {
        LOADB(A, 0);
        CONSUME(A, 0);
    }

    // tail (0..3 edges)
    for (int i = beg + (nb << 2); i < end; ++i) {
        const int iu = __builtin_amdgcn_readfirstlane(i);
        const int o = soff[iu];
        const uint32_t* gg = gbuf + o + ch;
        const uint32_t p0 = gg[0], p1 = gg[128], p2 = gg[256];
        const float* cp = coef + (size_t)iu * CSTRIDE;
        const float ux = cp[0], uy = cp[1], uz = cp[2], fc = cp[3];
        float W0 = fc * wr0[NRBF];
        float W1 = fc * wr1[NRBF];
        float W2 = fc * wr2[NRBF];
        #pragma unroll
        for (int n = 0; n < NRBF; ++n) {
            const float c = cp[4 + n];
            W0 += c * wr0[n];
            W1 += c * wr1[n];
            W2 += c * wr2[n];
        }
        const float xv = blo(p0) * W0;
        const float xs = bhi(p0) * W1;
        const float xd = blo(p1) * W2;
        a0 += bhi(p1) * xv + ux * xd;
        a1 += blo(p2) * xv + uy * xd;
        a2 += bhi(p2) * xv + uz * xd;
        as += xs;
    }

#undef LOADB
#undef CONSUME

    const size_t orow = (size_t)node * 384;
    dv[orow + ch]       = a0;
    dv[orow + 128 + ch] = a1;
    dv[orow + 256 + ch] = a2;
    ds[(size_t)node * HID + ch] = as;
}

extern "C" void kernel_launch(void* const* d_in, const int* in_sizes, int n_in,
                              void* d_out, int out_size, void* d_ws, size_t ws_size,
                              hipStream_t stream)
{
    const float* s    = (const float*)d_in[0];
    const float* v    = (const float*)d_in[1];
    const float* r_ij = (const float*)d_in[2];
    const int*   esrc = (const int*)d_in[3];
    const int*   edst = (const int*)d_in[4];
    const float* W1   = (const float*)d_in[5];
    const float* b1   = (const float*)d_in[6];
    const float* W2   = (const float*)d_in[7];
    const float* b2   = (const float*)d_in[8];
    const float* Wrbf = (const float*)d_in[9];
    const float* brbf = (const float*)d_in[10];

    float* out = (float*)d_out;
    float* dv  = out;                                   // (16384,3,128)
    float* ds  = out + (size_t)N_NODES * 3 * HID;       // (16384,128)

    // workspace layout — 128 B pad after row_ptr so row_ptr[16384] cannot
    // alias cur[0] (the R4 crash).
    char* ws = (char*)d_ws;
    uint32_t* g       = (uint32_t*)(ws + 0);            // 25,165,824 B
    float*    coef    = (float*)   (ws + 25165824);     // 25,165,824 B
    int*      soff    = (int*)     (ws + 50331648);     //  1,048,576 B
    int*      cnt     = (int*)     (ws + 51380224);     //     65,536 B
    int*      row_ptr = (int*)     (ws + 51445760);     //     65,540 B used
    int*      cur     = (int*)     (ws + 51511424);     //     65,536 B

    hipMemsetAsync(cnt, 0, 16384 * sizeof(int), stream);

    phi_kernel<<<N_NODES / NB, 128, 0, stream>>>(s, v, W1, b1, W2, b2, g);
    hist_kernel<<<N_EDGES / 256, 256, 0, stream>>>(edst, cnt);
    scan_kernel<<<1, 256, 0, stream>>>(cnt, row_ptr, cur);
    scatter_kernel<<<N_EDGES / 256, 256, 0, stream>>>(r_ij, esrc, edst, cur,
                                                      soff, coef);
    gather_kernel<<<N_NODES / 2, 256, 0, stream>>>(g, soff, coef, row_ptr,
                                                   Wrbf, brbf, dv, ds);
}

// Round 8
// 203.062 us; speedup vs baseline: 1.1310x; 1.1310x over previous
//
#include <hip/hip_runtime.h>
#include <math.h>
#include <stdint.h>

#define N_NODES 16384
#define N_EDGES 262144
#define HID 128
#define NRBF 20
#define CUTOFF 5.0f
#define PI_F 3.14159265358979323846f

// coef record: 16 uint32 = 64 B:
// [0..2]=ux,uy,uz (f32 bits) [3]=fcut (f32 bits)
// [4..13] = c0..c19 as f16 pairs   [14,15] = pad
#define CSTRIDE 16

typedef __attribute__((ext_vector_type(2))) __fp16 half2_t;
union U32H2 { uint32_t u; half2_t h; float f; };

__device__ inline unsigned short f2bf(float f) {
    unsigned int u = __float_as_uint(f);
    u = u + 0x7FFFu + ((u >> 16) & 1u);
    return (unsigned short)(u >> 16);
}
__device__ inline uint32_t pack2(float lo, float hi) {
    return (uint32_t)f2bf(lo) | ((uint32_t)f2bf(hi) << 16);
}
__device__ inline float blo(uint32_t u) { return __uint_as_float(u << 16); }
__device__ inline float bhi(uint32_t u) { return __uint_as_float(u & 0xFFFF0000u); }

// ---------------------------------------------------------------------------
// Kernel 1: phi = silu(s@W1+b1)@W2+b2, packed with v as bf16 pairs into
// g[node][384]: (phi0,phi1)(phi2,v0)(v1,v2)
// ---------------------------------------------------------------------------
#define NB 16
__global__ __launch_bounds__(128) void phi_kernel(
    const float* __restrict__ s, const float* __restrict__ v,
    const float* __restrict__ W1, const float* __restrict__ b1,
    const float* __restrict__ W2, const float* __restrict__ b2,
    uint32_t* __restrict__ g)
{
    __shared__ float sL[NB][HID];
    __shared__ float hL[NB][HID];
    const int t = threadIdx.x;
    const int node0 = blockIdx.x * NB;

    #pragma unroll
    for (int i = 0; i < NB; ++i)
        sL[i][t] = s[(size_t)(node0 + i) * HID + t];
    __syncthreads();

    float h[NB];
    const float bb1 = b1[t];
    #pragma unroll
    for (int i = 0; i < NB; ++i) h[i] = bb1;

    for (int k = 0; k < HID; k += 4) {
        float w[4];
        #pragma unroll
        for (int j = 0; j < 4; ++j) w[j] = W1[(size_t)(k + j) * HID + t];
        #pragma unroll
        for (int i = 0; i < NB; ++i) {
            const float4 sv = *reinterpret_cast<const float4*>(&sL[i][k]);
            h[i] += sv.x * w[0] + sv.y * w[1] + sv.z * w[2] + sv.w * w[3];
        }
    }
    #pragma unroll
    for (int i = 0; i < NB; ++i) {
        const float x = h[i];
        h[i] = x / (1.0f + expf(-x));
    }
    #pragma unroll
    for (int i = 0; i < NB; ++i) hL[i][t] = h[i];
    __syncthreads();

    float a0[NB], a1[NB], a2[NB];
    #pragma unroll
    for (int i = 0; i < NB; ++i) { a0[i] = 0.f; a1[i] = 0.f; a2[i] = 0.f; }

    for (int k = 0; k < HID; k += 4) {
        float w0[4], w1[4], w2[4];
        #pragma unroll
        for (int j = 0; j < 4; ++j) {
            const size_t row = (size_t)(k + j) * 384;
            w0[j] = W2[row + t];
            w1[j] = W2[row + 128 + t];
            w2[j] = W2[row + 256 + t];
        }
        #pragma unroll
        for (int i = 0; i < NB; ++i) {
            const float4 hv = *reinterpret_cast<const float4*>(&hL[i][k]);
            a0[i] += hv.x * w0[0] + hv.y * w0[1] + hv.z * w0[2] + hv.w * w0[3];
            a1[i] += hv.x * w1[0] + hv.y * w1[1] + hv.z * w1[2] + hv.w * w1[3];
            a2[i] += hv.x * w2[0] + hv.y * w2[1] + hv.z * w2[2] + hv.w * w2[3];
        }
    }
    const float bb2a = b2[t], bb2b = b2[128 + t], bb2c = b2[256 + t];
    #pragma unroll
    for (int i = 0; i < NB; ++i) {
        const size_t nrow = (size_t)(node0 + i) * 384;
        const float p0 = a0[i] + bb2a;
        const float p1 = a1[i] + bb2b;
        const float p2 = a2[i] + bb2c;
        const float v0 = v[nrow + t];
        const float v1 = v[nrow + 128 + t];
        const float v2 = v[nrow + 256 + t];
        g[nrow + t]       = pack2(p0, p1);
        g[nrow + 128 + t] = pack2(p2, v0);
        g[nrow + 256 + t] = pack2(v1, v2);
    }
}

// ---------------------------------------------------------------------------
// CSR build: histogram -> scan -> scatter (SoA: soff[]=src*384 + coef[])
// ---------------------------------------------------------------------------
__global__ __launch_bounds__(256) void hist_kernel(const int* __restrict__ edst,
                                                   int* __restrict__ cnt)
{
    const int e = blockIdx.x * 256 + threadIdx.x;
    if (e < N_EDGES) atomicAdd(&cnt[edst[e]], 1);
}

__global__ __launch_bounds__(256) void scan_kernel(const int* __restrict__ cnt,
                                                   int* __restrict__ row_ptr,
                                                   int* __restrict__ cur)
{
    __shared__ int part[256];
    const int tid = threadIdx.x;
    const int4* c4 = (const int4*)cnt;

    int4 loc[16];
    int s = 0;
    #pragma unroll
    for (int j = 0; j < 16; ++j) {
        loc[j] = c4[tid * 16 + j];
        s += loc[j].x + loc[j].y + loc[j].z + loc[j].w;
    }
    part[tid] = s;
    __syncthreads();
    #pragma unroll
    for (int d = 1; d < 256; d <<= 1) {
        const int add = (tid >= d) ? part[tid - d] : 0;
        __syncthreads();
        part[tid] += add;
        __syncthreads();
    }
    int off = (tid == 0) ? 0 : part[tid - 1];
    const int base = tid * 64;
    #pragma unroll
    for (int j = 0; j < 16; ++j) {
        const int4 q = loc[j];
        row_ptr[base + j*4 + 0] = off; cur[base + j*4 + 0] = off; off += q.x;
        row_ptr[base + j*4 + 1] = off; cur[base + j*4 + 1] = off; off += q.y;
        row_ptr[base + j*4 + 2] = off; cur[base + j*4 + 2] = off; off += q.z;
        row_ptr[base + j*4 + 3] = off; cur[base + j*4 + 3] = off; off += q.w;
    }
    if (tid == 255) row_ptr[16384] = off;
}

__global__ __launch_bounds__(256) void scatter_kernel(
    const float* __restrict__ r_ij, const int* __restrict__ esrc,
    const int* __restrict__ edst, int* __restrict__ cur,
    int* __restrict__ soff, uint32_t* __restrict__ coef)
{
    const int e = blockIdx.x * 256 + threadIdx.x;
    if (e >= N_EDGES) return;
    const float rx = r_ij[(size_t)e * 3 + 0];
    const float ry = r_ij[(size_t)e * 3 + 1];
    const float rz = r_ij[(size_t)e * 3 + 2];
    const float d = sqrtf(rx * rx + ry * ry + rz * rz);
    const float inv_d = 1.0f / d;
    float sx, cx;
    sincosf((PI_F / CUTOFF) * d, &sx, &cx);
    const float fcut = (d < CUTOFF) ? 0.5f * (cx + 1.0f) : 0.0f;

    float cf[NRBF];
    const float gfac = inv_d * fcut;
    const float twocx = 2.0f * cx;
    float sm1 = sx, sm2 = 0.0f;
    cf[0] = sx * gfac;
    #pragma unroll
    for (int n = 1; n < NRBF; ++n) {
        const float sn = twocx * sm1 - sm2;
        sm2 = sm1; sm1 = sn;
        cf[n] = sn * gfac;
    }

    // pack c0..c19 as f16 pairs (v_cvt_pkrtz_f16_f32)
    uint32_t cp[10];
    #pragma unroll
    for (int j = 0; j < 10; ++j) {
        U32H2 u;
        u.h = __builtin_amdgcn_cvt_pkrtz(cf[2 * j], cf[2 * j + 1]);
        cp[j] = u.u;
    }

    const int pos = atomicAdd(&cur[edst[e]], 1);
    soff[pos] = esrc[e] * 384;          // pre-scaled row offset
    uint4* c4 = (uint4*)(coef + (size_t)pos * CSTRIDE);
    c4[0] = make_uint4(__float_as_uint(rx * inv_d), __float_as_uint(ry * inv_d),
                       __float_as_uint(rz * inv_d), __float_as_uint(fcut));
    c4[1] = make_uint4(cp[0], cp[1], cp[2], cp[3]);
    c4[2] = make_uint4(cp[4], cp[5], cp[6], cp[7]);
    c4[3] = make_uint4(cp[8], cp[9], 0u, 0u);
}

// ---------------------------------------------------------------------------
// Gather: node per 128-thread group; batch-4 edges; depth-3 ping-pong
// prefetch (36 gather words in flight); scalar coef/soff loads; filter
// matvec via v_dot2_f32_f16 (2 MACs/instr).
// ---------------------------------------------------------------------------
__global__ __launch_bounds__(256, 4) void gather_kernel(
    const uint32_t* __restrict__ gbuf, const int* __restrict__ soff,
    const uint32_t* __restrict__ coef, const int* __restrict__ row_ptr,
    const float* __restrict__ Wrbf, const float* __restrict__ brbf,
    float* __restrict__ dv, float* __restrict__ ds)
{
    const int ch   = threadIdx.x & 127;
    const int node = blockIdx.x * 2 + (threadIdx.x >> 7);

    // filter weights packed as f16 pairs: 10 pairs per output channel row
    half2_t wp0[10], wp1[10], wp2[10];
    #pragma unroll
    for (int j = 0; j < 10; ++j) {
        wp0[j] = __builtin_amdgcn_cvt_pkrtz(Wrbf[(2*j) * 384 + ch],
                                            Wrbf[(2*j+1) * 384 + ch]);
        wp1[j] = __builtin_amdgcn_cvt_pkrtz(Wrbf[(2*j) * 384 + 128 + ch],
                                            Wrbf[(2*j+1) * 384 + 128 + ch]);
        wp2[j] = __builtin_amdgcn_cvt_pkrtz(Wrbf[(2*j) * 384 + 256 + ch],
                                            Wrbf[(2*j+1) * 384 + 256 + ch]);
    }
    const float br0 = brbf[ch], br1 = brbf[128 + ch], br2 = brbf[256 + ch];

    const int beg = row_ptr[node];
    const int end = row_ptr[node + 1];
    const int nb  = (end - beg) >> 2;

    float a0 = 0.f, a1 = 0.f, a2 = 0.f, as = 0.f;

    uint32_t A[12], B[12], C[12];

#define LOADB(P, bi) do {                                                     \
    const int* sp_ = soff + __builtin_amdgcn_readfirstlane(beg + (bi) * 4);   \
    const uint32_t* g0_ = gbuf + sp_[0] + ch;                                 \
    const uint32_t* g1_ = gbuf + sp_[1] + ch;                                 \
    const uint32_t* g2_ = gbuf + sp_[2] + ch;                                 \
    const uint32_t* g3_ = gbuf + sp_[3] + ch;                                 \
    P[0] = g0_[0]; P[1]  = g0_[128]; P[2]  = g0_[256];                        \
    P[3] = g1_[0]; P[4]  = g1_[128]; P[5]  = g1_[256];                        \
    P[6] = g2_[0]; P[7]  = g2_[128]; P[8]  = g2_[256];                        \
    P[9] = g3_[0]; P[10] = g3_[128]; P[11] = g3_[256];                        \
} while (0)

#define CONSUME(P, bi) do {                                                   \
    const uint32_t* cp_ = coef +                                              \
        (size_t)__builtin_amdgcn_readfirstlane(beg + (bi) * 4) * CSTRIDE;     \
    _Pragma("unroll")                                                         \
    for (int k = 0; k < 4; ++k) {                                             \
        const float ux = __uint_as_float(cp_[k * CSTRIDE + 0]);               \
        const float uy = __uint_as_float(cp_[k * CSTRIDE + 1]);               \
        const float uz = __uint_as_float(cp_[k * CSTRIDE + 2]);               \
        const float fc = __uint_as_float(cp_[k * CSTRIDE + 3]);               \
        float W0 = fc * br0;                                                  \
        float W1 = fc * br1;                                                  \
        float W2 = fc * br2;                                                  \
        _Pragma("unroll")                                                     \
        for (int j = 0; j < 10; ++j) {                                        \
            U32H2 cc; cc.u = cp_[k * CSTRIDE + 4 + j];                        \
            W0 = __builtin_amdgcn_fdot2(cc.h, wp0[j], W0, false);             \
            W1 = __builtin_amdgcn_fdot2(cc.h, wp1[j], W1, false);             \
            W2 = __builtin_amdgcn_fdot2(cc.h, wp2[j], W2, false);             \
        }                                                                     \
        const uint32_t p0 = P[k*3], p1 = P[k*3+1], p2 = P[k*3+2];             \
        const float xv = blo(p0) * W0;                                        \
        const float xs = bhi(p0) * W1;                                        \
        const float xd = blo(p1) * W2;                                        \
        a0 += bhi(p1) * xv + ux * xd;                                         \
        a1 += blo(p2) * xv + uy * xd;                                         \
        a2 += bhi(p2) * xv + uz * xd;                                         \
        as += xs;                                                             \
    }                                                                         \
} while (0)

    if (nb > 0) {
        const int last = nb - 1;
        LOADB(A, 0);
        LOADB(B, (1 < last ? 1 : last));
        LOADB(C, (2 < last ? 2 : last));
        int b = 0;
        for (; b + 3 < nb; b += 3) {
            CONSUME(A, b);
            LOADB(A, b + 3);
            CONSUME(B, b + 1);
            LOADB(B, (b + 4 < last ? b + 4 : last));
            CONSUME(C, b + 2);
            LOADB(C, (b + 5 < last ? b + 5 : last));
        }
        const int rem = nb - b;
        CONSUME(A, b);
        if (rem >= 2) CONSUME(B, b + 1);
        if (rem == 3) CONSUME(C, b + 2);
    }

    // tail (0..3 edges)
    for (int i = beg + (nb << 2); i < end; ++i) {
        const int iu = __builtin_amdgcn_readfirstlane(i);
        const int o = soff[iu];
        const uint32_t* gg = gbuf + o + ch;
        const uint32_t p0 = gg[0], p1 = gg[128], p2 = gg[256];
        const uint32_t* cp = coef + (size_t)iu * CSTRIDE;
        const float ux = __uint_as_float(cp[0]);
        const float uy = __uint_as_float(cp[1]);
        const float uz = __uint_as_float(cp[2]);
        const float fc = __uint_as_float(cp[3]);
        float W0 = fc * br0;
        float W1 = fc * br1;
        float W2 = fc * br2;
        #pragma unroll
        for (int j = 0; j < 10; ++j) {
            U32H2 cc; cc.u = cp[4 + j];
            W0 = __builtin_amdgcn_fdot2(cc.h, wp0[j], W0, false);
            W1 = __builtin_amdgcn_fdot2(cc.h, wp1[j], W1, false);
            W2 = __builtin_amdgcn_fdot2(cc.h, wp2[j], W2, false);
        }
        const float xv = blo(p0) * W0;
        const float xs = bhi(p0) * W1;
        const float xd = blo(p1) * W2;
        a0 += bhi(p1) * xv + ux * xd;
        a1 += blo(p2) * xv + uy * xd;
        a2 += bhi(p2) * xv + uz * xd;
        as += xs;
    }

#undef LOADB
#undef CONSUME

    const size_t orow = (size_t)node * 384;
    dv[orow + ch]       = a0;
    dv[orow + 128 + ch] = a1;
    dv[orow + 256 + ch] = a2;
    ds[(size_t)node * HID + ch] = as;
}

extern "C" void kernel_launch(void* const* d_in, const int* in_sizes, int n_in,
                              void* d_out, int out_size, void* d_ws, size_t ws_size,
                              hipStream_t stream)
{
    const float* s    = (const float*)d_in[0];
    const float* v    = (const float*)d_in[1];
    const float* r_ij = (const float*)d_in[2];
    const int*   esrc = (const int*)d_in[3];
    const int*   edst = (const int*)d_in[4];
    const float* W1   = (const float*)d_in[5];
    const float* b1   = (const float*)d_in[6];
    const float* W2   = (const float*)d_in[7];
    const float* b2   = (const float*)d_in[8];
    const float* Wrbf = (const float*)d_in[9];
    const float* brbf = (const float*)d_in[10];

    float* out = (float*)d_out;
    float* dv  = out;                                   // (16384,3,128)
    float* ds  = out + (size_t)N_NODES * 3 * HID;       // (16384,128)

    // workspace layout — 128 B pad after row_ptr so row_ptr[16384] cannot
    // alias cur[0] (the R4 crash).
    char* ws = (char*)d_ws;
    uint32_t* g       = (uint32_t*)(ws + 0);            // 25,165,824 B
    uint32_t* coef    = (uint32_t*)(ws + 25165824);     // 16,777,216 B
    int*      soff    = (int*)     (ws + 41943040);     //  1,048,576 B
    int*      cnt     = (int*)     (ws + 42991616);     //     65,536 B
    int*      row_ptr = (int*)     (ws + 43057152);     //     65,540 B used
    int*      cur     = (int*)     (ws + 43122816);     //     65,536 B

    hipMemsetAsync(cnt, 0, 16384 * sizeof(int), stream);

    phi_kernel<<<N_NODES / NB, 128, 0, stream>>>(s, v, W1, b1, W2, b2, g);
    hist_kernel<<<N_EDGES / 256, 256, 0, stream>>>(edst, cnt);
    scan_kernel<<<1, 256, 0, stream>>>(cnt, row_ptr, cur);
    scatter_kernel<<<N_EDGES / 256, 256, 0, stream>>>(r_ij, esrc, edst, cur,
                                                      soff, coef);
    gather_kernel<<<N_NODES / 2, 256, 0, stream>>>(g, soff, coef, row_ptr,
                                                   Wrbf, brbf, dv, ds);
}

// Round 9
// 190.666 us; speedup vs baseline: 1.2046x; 1.0650x over previous
//
#include <hip/hip_runtime.h>
#include <math.h>
#include <stdint.h>

#define N_NODES 16384
#define N_EDGES 262144
#define HID 128
#define NRBF 20
#define CUTOFF 5.0f
#define PI_F 3.14159265358979323846f

// coef record: 16 uint32 = 64 B:
// [0..2]=ux,uy,uz (f32 bits) [3]=fcut (f32 bits)
// [4..13] = c0..c19 as f16 pairs   [14,15] = pad
#define CSTRIDE 16

typedef __attribute__((ext_vector_type(2))) __fp16 half2_t;
union U32H2 { uint32_t u; half2_t h; float f; };

__device__ inline unsigned short f2bf(float f) {
    unsigned int u = __float_as_uint(f);
    u = u + 0x7FFFu + ((u >> 16) & 1u);
    return (unsigned short)(u >> 16);
}
__device__ inline uint32_t pack2(float lo, float hi) {
    return (uint32_t)f2bf(lo) | ((uint32_t)f2bf(hi) << 16);
}
__device__ inline float blo(uint32_t u) { return __uint_as_float(u << 16); }
__device__ inline float bhi(uint32_t u) { return __uint_as_float(u & 0xFFFF0000u); }

// ---------------------------------------------------------------------------
// Kernel 1: phi = silu(s@W1+b1)@W2+b2 via v_dot2_f32_f16, fused histogram.
// Output: g4[node*128+ch] = uint4{(phi0,phi1),(phi2,v0),(v1,v2),0} bf16 pairs.
// 1024 blocks x 128 threads; each block also histograms 256 edges.
// ---------------------------------------------------------------------------
#define NB 16
__global__ __launch_bounds__(128) void phi_kernel(
    const float* __restrict__ s, const float* __restrict__ v,
    const float* __restrict__ W1, const float* __restrict__ b1,
    const float* __restrict__ W2, const float* __restrict__ b2,
    const int* __restrict__ edst, int* __restrict__ cnt,
    uint4* __restrict__ g4)
{
    const int t = threadIdx.x;
    const int node0 = blockIdx.x * NB;

    // fused edge histogram: 1024 blocks x 256 edges covers N_EDGES exactly
    {
        const int e0 = blockIdx.x * 256 + t;
        atomicAdd(&cnt[edst[e0]], 1);
        atomicAdd(&cnt[edst[e0 + 128]], 1);
    }

    __shared__ uint32_t sL2[NB][64];    // s rows packed as f16 pairs
    __shared__ float    hL[NB][HID];
    __shared__ uint32_t hL2[NB][64];    // h rows packed as f16 pairs

    if (t < 64) {
        #pragma unroll
        for (int i = 0; i < NB; ++i) {
            const float2 sv = *(const float2*)&s[(size_t)(node0 + i) * HID + 2 * t];
            U32H2 u; u.h = __builtin_amdgcn_cvt_pkrtz(sv.x, sv.y);
            sL2[i][t] = u.u;
        }
    }
    __syncthreads();

    // phase 1: h = silu(s @ W1 + b1), thread t = output channel
    float h[NB];
    const float bb1 = b1[t];
    #pragma unroll
    for (int i = 0; i < NB; ++i) h[i] = bb1;

    for (int kp = 0; kp < 64; kp += 2) {
        const float w0 = W1[(size_t)(2 * kp) * HID + t];
        const float w1 = W1[(size_t)(2 * kp + 1) * HID + t];
        const float w2 = W1[(size_t)(2 * kp + 2) * HID + t];
        const float w3 = W1[(size_t)(2 * kp + 3) * HID + t];
        const half2_t wa = __builtin_amdgcn_cvt_pkrtz(w0, w1);
        const half2_t wb = __builtin_amdgcn_cvt_pkrtz(w2, w3);
        #pragma unroll
        for (int i = 0; i < NB; ++i) {
            U32H2 ca; ca.u = sL2[i][kp];
            U32H2 cb; cb.u = sL2[i][kp + 1];
            h[i] = __builtin_amdgcn_fdot2(ca.h, wa, h[i], false);
            h[i] = __builtin_amdgcn_fdot2(cb.h, wb, h[i], false);
        }
    }
    #pragma unroll
    for (int i = 0; i < NB; ++i) {
        const float x = h[i];
        h[i] = x / (1.0f + expf(-x));
        hL[i][t] = h[i];
    }
    __syncthreads();
    if (t < 64) {
        #pragma unroll
        for (int i = 0; i < NB; ++i) {
            U32H2 u; u.h = __builtin_amdgcn_cvt_pkrtz(hL[i][2 * t], hL[i][2 * t + 1]);
            hL2[i][t] = u.u;
        }
    }
    __syncthreads();

    // phase 2: phi = h @ W2 + b2; thread t owns output channels t, t+128, t+256
    float a0[NB], a1[NB], a2[NB];
    #pragma unroll
    for (int i = 0; i < NB; ++i) { a0[i] = 0.f; a1[i] = 0.f; a2[i] = 0.f; }

    for (int kp = 0; kp < 64; ++kp) {
        const size_t r0 = (size_t)(2 * kp) * 384;
        const size_t r1 = r0 + 384;
        const half2_t wA = __builtin_amdgcn_cvt_pkrtz(W2[r0 + t],       W2[r1 + t]);
        const half2_t wB = __builtin_amdgcn_cvt_pkrtz(W2[r0 + 128 + t], W2[r1 + 128 + t]);
        const half2_t wC = __builtin_amdgcn_cvt_pkrtz(W2[r0 + 256 + t], W2[r1 + 256 + t]);
        #pragma unroll
        for (int i = 0; i < NB; ++i) {
            U32H2 hh; hh.u = hL2[i][kp];
            a0[i] = __builtin_amdgcn_fdot2(hh.h, wA, a0[i], false);
            a1[i] = __builtin_amdgcn_fdot2(hh.h, wB, a1[i], false);
            a2[i] = __builtin_amdgcn_fdot2(hh.h, wC, a2[i], false);
        }
    }
    const float bb2a = b2[t], bb2b = b2[128 + t], bb2c = b2[256 + t];
    #pragma unroll
    for (int i = 0; i < NB; ++i) {
        const size_t nrow = (size_t)(node0 + i) * 384;
        const float p0 = a0[i] + bb2a;
        const float p1 = a1[i] + bb2b;
        const float p2 = a2[i] + bb2c;
        const float v0 = v[nrow + t];
        const float v1 = v[nrow + 128 + t];
        const float v2 = v[nrow + 256 + t];
        g4[(size_t)(node0 + i) * HID + t] =
            make_uint4(pack2(p0, p1), pack2(p2, v0), pack2(v1, v2), 0u);
    }
}

// ---------------------------------------------------------------------------
// CSR build: scan -> scatter (SoA: soff[]=src*128 uint4-rows + coef[])
// ---------------------------------------------------------------------------
__global__ __launch_bounds__(256) void scan_kernel(const int* __restrict__ cnt,
                                                   int* __restrict__ row_ptr,
                                                   int* __restrict__ cur)
{
    __shared__ int part[256];
    const int tid = threadIdx.x;
    const int4* c4 = (const int4*)cnt;

    int4 loc[16];
    int s = 0;
    #pragma unroll
    for (int j = 0; j < 16; ++j) {
        loc[j] = c4[tid * 16 + j];
        s += loc[j].x + loc[j].y + loc[j].z + loc[j].w;
    }
    part[tid] = s;
    __syncthreads();
    #pragma unroll
    for (int d = 1; d < 256; d <<= 1) {
        const int add = (tid >= d) ? part[tid - d] : 0;
        __syncthreads();
        part[tid] += add;
        __syncthreads();
    }
    int off = (tid == 0) ? 0 : part[tid - 1];
    const int base = tid * 64;
    #pragma unroll
    for (int j = 0; j < 16; ++j) {
        const int4 q = loc[j];
        row_ptr[base + j*4 + 0] = off; cur[base + j*4 + 0] = off; off += q.x;
        row_ptr[base + j*4 + 1] = off; cur[base + j*4 + 1] = off; off += q.y;
        row_ptr[base + j*4 + 2] = off; cur[base + j*4 + 2] = off; off += q.z;
        row_ptr[base + j*4 + 3] = off; cur[base + j*4 + 3] = off; off += q.w;
    }
    if (tid == 255) row_ptr[16384] = off;
}

__global__ __launch_bounds__(256) void scatter_kernel(
    const float* __restrict__ r_ij, const int* __restrict__ esrc,
    const int* __restrict__ edst, int* __restrict__ cur,
    int* __restrict__ soff, uint32_t* __restrict__ coef)
{
    const int e = blockIdx.x * 256 + threadIdx.x;
    if (e >= N_EDGES) return;
    const float rx = r_ij[(size_t)e * 3 + 0];
    const float ry = r_ij[(size_t)e * 3 + 1];
    const float rz = r_ij[(size_t)e * 3 + 2];
    const float d = sqrtf(rx * rx + ry * ry + rz * rz);
    const float inv_d = 1.0f / d;
    float sx, cx;
    sincosf((PI_F / CUTOFF) * d, &sx, &cx);
    const float fcut = (d < CUTOFF) ? 0.5f * (cx + 1.0f) : 0.0f;

    float cf[NRBF];
    const float gfac = inv_d * fcut;
    const float twocx = 2.0f * cx;
    float sm1 = sx, sm2 = 0.0f;
    cf[0] = sx * gfac;
    #pragma unroll
    for (int n = 1; n < NRBF; ++n) {
        const float sn = twocx * sm1 - sm2;
        sm2 = sm1; sm1 = sn;
        cf[n] = sn * gfac;
    }

    uint32_t cp[10];
    #pragma unroll
    for (int j = 0; j < 10; ++j) {
        U32H2 u;
        u.h = __builtin_amdgcn_cvt_pkrtz(cf[2 * j], cf[2 * j + 1]);
        cp[j] = u.u;
    }

    const int pos = atomicAdd(&cur[edst[e]], 1);
    soff[pos] = esrc[e] * 128;          // uint4-row offset
    uint4* c4 = (uint4*)(coef + (size_t)pos * CSTRIDE);
    c4[0] = make_uint4(__float_as_uint(rx * inv_d), __float_as_uint(ry * inv_d),
                       __float_as_uint(rz * inv_d), __float_as_uint(fcut));
    c4[1] = make_uint4(cp[0], cp[1], cp[2], cp[3]);
    c4[2] = make_uint4(cp[4], cp[5], cp[6], cp[7]);
    c4[3] = make_uint4(cp[8], cp[9], 0u, 0u);
}

// ---------------------------------------------------------------------------
// Gather: node per 128-thread group; batch-4 edges; depth-3 prefetch; ONE
// dwordx4 load per edge-thread; scalar coef/soff loads; fdot2 filter matvec.
// ---------------------------------------------------------------------------
__global__ __launch_bounds__(256, 4) void gather_kernel(
    const uint4* __restrict__ g4, const int* __restrict__ soff,
    const uint32_t* __restrict__ coef, const int* __restrict__ row_ptr,
    const float* __restrict__ Wrbf, const float* __restrict__ brbf,
    float* __restrict__ dv, float* __restrict__ ds)
{
    const int ch   = threadIdx.x & 127;
    const int node = blockIdx.x * 2 + (threadIdx.x >> 7);

    half2_t wp0[10], wp1[10], wp2[10];
    #pragma unroll
    for (int j = 0; j < 10; ++j) {
        wp0[j] = __builtin_amdgcn_cvt_pkrtz(Wrbf[(2*j) * 384 + ch],
                                            Wrbf[(2*j+1) * 384 + ch]);
        wp1[j] = __builtin_amdgcn_cvt_pkrtz(Wrbf[(2*j) * 384 + 128 + ch],
                                            Wrbf[(2*j+1) * 384 + 128 + ch]);
        wp2[j] = __builtin_amdgcn_cvt_pkrtz(Wrbf[(2*j) * 384 + 256 + ch],
                                            Wrbf[(2*j+1) * 384 + 256 + ch]);
    }
    const float br0 = brbf[ch], br1 = brbf[128 + ch], br2 = brbf[256 + ch];

    const int beg = row_ptr[node];
    const int end = row_ptr[node + 1];
    const int nb  = (end - beg) >> 2;

    float a0 = 0.f, a1 = 0.f, a2 = 0.f, as = 0.f;

    uint4 A[4], B[4], C[4];

#define LOADB(P, bi) do {                                                     \
    const int* sp_ = soff + __builtin_amdgcn_readfirstlane(beg + (bi) * 4);   \
    P[0] = g4[sp_[0] + ch];                                                   \
    P[1] = g4[sp_[1] + ch];                                                   \
    P[2] = g4[sp_[2] + ch];                                                   \
    P[3] = g4[sp_[3] + ch];                                                   \
} while (0)

#define CONSUME(P, bi) do {                                                   \
    const uint32_t* cp_ = coef +                                              \
        (size_t)__builtin_amdgcn_readfirstlane(beg + (bi) * 4) * CSTRIDE;     \
    _Pragma("unroll")                                                         \
    for (int k = 0; k < 4; ++k) {                                             \
        const float ux = __uint_as_float(cp_[k * CSTRIDE + 0]);               \
        const float uy = __uint_as_float(cp_[k * CSTRIDE + 1]);               \
        const float uz = __uint_as_float(cp_[k * CSTRIDE + 2]);               \
        const float fc = __uint_as_float(cp_[k * CSTRIDE + 3]);               \
        float W0 = fc * br0;                                                  \
        float W1 = fc * br1;                                                  \
        float W2 = fc * br2;                                                  \
        _Pragma("unroll")                                                     \
        for (int j = 0; j < 10; ++j) {                                        \
            U32H2 cc; cc.u = cp_[k * CSTRIDE + 4 + j];                        \
            W0 = __builtin_amdgcn_fdot2(cc.h, wp0[j], W0, false);             \
            W1 = __builtin_amdgcn_fdot2(cc.h, wp1[j], W1, false);             \
            W2 = __builtin_amdgcn_fdot2(cc.h, wp2[j], W2, false);             \
        }                                                                     \
        const uint32_t p0 = P[k].x, p1 = P[k].y, p2 = P[k].z;                 \
        const float xv = blo(p0) * W0;                                        \
        const float xs = bhi(p0) * W1;                                        \
        const float xd = blo(p1) * W2;                                        \
        a0 += bhi(p1) * xv + ux * xd;                                         \
        a1 += blo(p2) * xv + uy * xd;                                         \
        a2 += bhi(p2) * xv + uz * xd;                                         \
        as += xs;                                                             \
    }                                                                         \
} while (0)

    if (nb > 0) {
        const int last = nb - 1;
        LOADB(A, 0);
        LOADB(B, (1 < last ? 1 : last));
        LOADB(C, (2 < last ? 2 : last));
        int b = 0;
        for (; b + 3 < nb; b += 3) {
            CONSUME(A, b);
            LOADB(A, b + 3);
            CONSUME(B, b + 1);
            LOADB(B, (b + 4 < last ? b + 4 : last));
            CONSUME(C, b + 2);
            LOADB(C, (b + 5 < last ? b + 5 : last));
        }
        const int rem = nb - b;
        CONSUME(A, b);
        if (rem >= 2) CONSUME(B, b + 1);
        if (rem == 3) CONSUME(C, b + 2);
    }

    // tail (0..3 edges)
    for (int i = beg + (nb << 2); i < end; ++i) {
        const int iu = __builtin_amdgcn_readfirstlane(i);
        const uint4 P = g4[soff[iu] + ch];
        const uint32_t* cp = coef + (size_t)iu * CSTRIDE;
        const float ux = __uint_as_float(cp[0]);
        const float uy = __uint_as_float(cp[1]);
        const float uz = __uint_as_float(cp[2]);
        const float fc = __uint_as_float(cp[3]);
        float W0 = fc * br0;
        float W1 = fc * br1;
        float W2 = fc * br2;
        #pragma unroll
        for (int j = 0; j < 10; ++j) {
            U32H2 cc; cc.u = cp[4 + j];
            W0 = __builtin_amdgcn_fdot2(cc.h, wp0[j], W0, false);
            W1 = __builtin_amdgcn_fdot2(cc.h, wp1[j], W1, false);
            W2 = __builtin_amdgcn_fdot2(cc.h, wp2[j], W2, false);
        }
        const uint32_t p0 = P.x, p1 = P.y, p2 = P.z;
        const float xv = blo(p0) * W0;
        const float xs = bhi(p0) * W1;
        const float xd = blo(p1) * W2;
        a0 += bhi(p1) * xv + ux * xd;
        a1 += blo(p2) * xv + uy * xd;
        a2 += bhi(p2) * xv + uz * xd;
        as += xs;
    }

#undef LOADB
#undef CONSUME

    const size_t orow = (size_t)node * 384;
    dv[orow + ch]       = a0;
    dv[orow + 128 + ch] = a1;
    dv[orow + 256 + ch] = a2;
    ds[(size_t)node * HID + ch] = as;
}

extern "C" void kernel_launch(void* const* d_in, const int* in_sizes, int n_in,
                              void* d_out, int out_size, void* d_ws, size_t ws_size,
                              hipStream_t stream)
{
    const float* s    = (const float*)d_in[0];
    const float* v    = (const float*)d_in[1];
    const float* r_ij = (const float*)d_in[2];
    const int*   esrc = (const int*)d_in[3];
    const int*   edst = (const int*)d_in[4];
    const float* W1   = (const float*)d_in[5];
    const float* b1   = (const float*)d_in[6];
    const float* W2   = (const float*)d_in[7];
    const float* b2   = (const float*)d_in[8];
    const float* Wrbf = (const float*)d_in[9];
    const float* brbf = (const float*)d_in[10];

    float* out = (float*)d_out;
    float* dv  = out;                                   // (16384,3,128)
    float* ds  = out + (size_t)N_NODES * 3 * HID;       // (16384,128)

    // workspace layout — 124 B pad after row_ptr so row_ptr[16384] cannot
    // alias cur[0] (the R4 crash).
    char* ws = (char*)d_ws;
    uint4*    g4      = (uint4*)   (ws + 0);            // 33,554,432 B
    uint32_t* coef    = (uint32_t*)(ws + 33554432);     // 16,777,216 B
    int*      soff    = (int*)     (ws + 50331648);     //  1,048,576 B
    int*      cnt     = (int*)     (ws + 51380224);     //     65,536 B
    int*      row_ptr = (int*)     (ws + 51445760);     //     65,540 B used
    int*      cur     = (int*)     (ws + 51511424);     //     65,536 B

    hipMemsetAsync(cnt, 0, 16384 * sizeof(int), stream);

    phi_kernel<<<N_NODES / NB, 128, 0, stream>>>(s, v, W1, b1, W2, b2,
                                                 edst, cnt, g4);
    scan_kernel<<<1, 256, 0, stream>>>(cnt, row_ptr, cur);
    scatter_kernel<<<N_EDGES / 256, 256, 0, stream>>>(r_ij, esrc, edst, cur,
                                                      soff, coef);
    gather_kernel<<<N_NODES / 2, 256, 0, stream>>>(g4, soff, coef, row_ptr,
                                                   Wrbf, brbf, dv, ds);
}